// Round 7
// baseline (892.189 us; speedup 1.0000x reference)
//
#include <hip/hip_runtime.h>
#include <hip/hip_bf16.h>
#include <stdint.h>

#define T_TOK 131072
#define DIM   512
#define NBR   8
#define WIN   512                 // tokens per window
#define NWIN  (T_TOK / WIN)       // 256
#define SLCAP 640                 // padded slot capacity (40 slices of 16)
#define NSL   40
#define BK    32
#define NKT   (DIM / BK)          // 16

typedef __attribute__((ext_vector_type(8))) __bf16 bf16x8;
typedef __attribute__((ext_vector_type(4))) float  f32x4;
typedef unsigned short ushort_t;

__device__ __forceinline__ unsigned short f2bf(float f) {
  union { float f; unsigned int u; } v; v.f = f;
  unsigned int r = v.u + 0x7fffu + ((v.u >> 16) & 1u);
  return (unsigned short)(r >> 16);
}

// ---------- W transpose: (N,D,D) f32 -> Wt bf16 [b][kt][col][kk] ----------
__global__ __launch_bounds__(256) void k_wtrans(const float* __restrict__ W,
                                                ushort_t* __restrict__ Wt) {
  __shared__ float tile[BK][129];
  int blk = blockIdx.x;          // 8 * 16 * 4 = 512 blocks
  int b  = blk >> 6;
  int kt = (blk >> 2) & 15;
  int cb = blk & 3;
  int t = threadIdx.x;
  #pragma unroll
  for (int i = 0; i < 4; ++i) {
    int idx4 = i * 256 + t;
    int kr = idx4 >> 5;
    int c4 = idx4 & 31;
    const float* src = W + (((size_t)b * DIM + (size_t)(kt * BK + kr)) * DIM + cb * 128 + c4 * 4);
    float4 v = *(const float4*)src;
    tile[kr][c4 * 4 + 0] = v.x;
    tile[kr][c4 * 4 + 1] = v.y;
    tile[kr][c4 * 4 + 2] = v.z;
    tile[kr][c4 * 4 + 3] = v.w;
  }
  __syncthreads();
  int c  = t >> 1;
  int kh = t & 1;
  unsigned int p[8];
  #pragma unroll
  for (int i = 0; i < 8; ++i) {
    unsigned short lo = f2bf(tile[kh * 16 + i * 2 + 0][c]);
    unsigned short hi = f2bf(tile[kh * 16 + i * 2 + 1][c]);
    p[i] = (unsigned int)lo | ((unsigned int)hi << 16);
  }
  size_t obase = (((size_t)b * 16 + kt) * DIM + (size_t)(cb * 128 + c)) * BK + kh * 16;
  uint4 q0; q0.x = p[0]; q0.y = p[1]; q0.z = p[2]; q0.w = p[3];
  uint4 q1; q1.x = p[4]; q1.y = p[5]; q1.z = p[6]; q1.w = p[7];
  *(uint4*)&Wt[obase]     = q0;
  *(uint4*)&Wt[obase + 8] = q1;
}

// ---------- per-window local sort: smap, slice->branch, slice count ----------
__global__ __launch_bounds__(WIN) void k_sort(const int* __restrict__ bidx,
                                              unsigned short* __restrict__ smap,
                                              int* __restrict__ sliceBr,
                                              int* __restrict__ tsArr) {
  __shared__ int cnt[NBR], ps[NBR], rankL[WIN], bidL[WIN];
  const int w = blockIdx.x;
  const int t = threadIdx.x;
  if (t < NBR) cnt[t] = 0;
  __syncthreads();
  int b = bidx[w * WIN + t];
  bidL[t] = b;
  rankL[t] = atomicAdd(&cnt[b], 1);
  __syncthreads();
  if (t == 0) {
    int s = 0;
    for (int g = 0; g < NBR; ++g) { ps[g] = s; s += (cnt[g] + 15) >> 4; }
    tsArr[w] = s;
  }
  __syncthreads();
  if (t < NSL) {
    int br = -1;
    #pragma unroll
    for (int g = 0; g < NBR; ++g) {
      int sc = (cnt[g] + 15) >> 4;
      if (t >= ps[g] && t < ps[g] + sc) br = g;
    }
    sliceBr[w * NSL + t] = br;
  }
  smap[w * WIN + t] = (unsigned short)(ps[bidL[t]] * 16 + rankL[t]);
}

// ---------- x (f32, natural order, streaming read) -> xT bf16 [w][kt][slot][kk] ----------
__global__ __launch_bounds__(512) void k_xcvt(const float* __restrict__ x,
                                              const unsigned short* __restrict__ smap,
                                              ushort_t* __restrict__ xT, int w0) {
  __shared__ unsigned short slotL[WIN];
  const int bid = blockIdx.x;
  const int w = w0 + (bid >> 2);
  const int part = bid & 3;
  const int t = threadIdx.x;
  slotL[t] = smap[w * WIN + t];
  __syncthreads();
  const float4* xp = (const float4*)(x + (size_t)w * (WIN * DIM));
  ushort_t* xTw = xT + (size_t)(w - w0) * (NKT * SLCAP * BK);
  #pragma unroll 4
  for (int i = 0; i < 32; ++i) {
    int fidx = part * 16384 + i * 512 + t;       // float4 index within window
    float4 v = xp[fidx];
    int row = fidx >> 7;
    int kq4 = fidx & 127;
    int kt = kq4 >> 3;
    int kk = (kq4 & 7) * 4;
    int slot = slotL[row];
    ushort4 a4;
    a4.x = f2bf(v.x); a4.y = f2bf(v.y); a4.z = f2bf(v.z); a4.w = f2bf(v.w);
    *(ushort4*)&xTw[((size_t)kt * SLCAP + slot) * BK + kk] = a4;
  }
}

// ---------- GEMM: col-blocks of a window co-dispatched (bid = w*4+cb) ----------
// 1024 thr = 16 waves = 8 slice-groups x 2 col-halves; wave tile 80x64.
// A-frags pipelined one kt ahead (L3-latency cover); B inline from L2-hot Wt.
__global__ __launch_bounds__(1024, 4)
void k_gemm(const ushort_t* __restrict__ xT, const ushort_t* __restrict__ Wt,
            const float* __restrict__ bias,
            const unsigned short* __restrict__ smap,
            const int* __restrict__ sliceBr, const int* __restrict__ tsArr,
            float* __restrict__ out, int w0) {
  __shared__ float OtL[128 * 130];
  __shared__ int sbrL[NSL];

  const int bid = blockIdx.x;
  const int wloc = bid >> 2;            // co-dispatch the 4 col-blocks of a window
  const int cb = bid & 3;
  const int w = w0 + wloc;
  const int t = threadIdx.x;
  const int l = t & 63;
  const int wv = t >> 6;
  const int ts = tsArr[w];

  if (t < NSL) sbrL[t] = sliceBr[w * NSL + t];
  const unsigned short myslot = smap[w * WIN + (t & 511)];
  __syncthreads();

  const int sg = wv >> 1;               // slice group 0..7
  const int ch = wv & 1;                // col half 0..1
  const int colbase = cb * 128 + ch * 64;

  const ushort_t* xTw = xT + (size_t)wloc * (NKT * SLCAP * BK);
  const int aoff = (l & 15) * BK + (l >> 4) * 8;
  int boff[4];
  #pragma unroll
  for (int cf = 0; cf < 4; ++cf)
    boff[cf] = (colbase + cf * 16 + (l & 15)) * BK + (l >> 4) * 8;

  f32x4 acc[5][4];
  #pragma unroll
  for (int s = 0; s < 5; ++s)
    #pragma unroll
    for (int cf = 0; cf < 4; ++cf) acc[s][cf] = (f32x4){0.f, 0.f, 0.f, 0.f};

  // prologue: A-frags for kt=0
  bf16x8 afc[5];
  #pragma unroll
  for (int s = 0; s < 5; ++s) {
    const int gs = sg * 5 + s;
    if (gs < ts) afc[s] = *(const bf16x8*)(xTw + gs * 512 + aoff);
  }

  for (int kt = 0; kt < NKT; ++kt) {
    // issue next kt's A-frags first; they fly under this kt's MFMA chain
    bf16x8 afn[5];
    if (kt + 1 < NKT) {
      const ushort_t* apn = xTw + (size_t)(kt + 1) * (SLCAP * BK);
      #pragma unroll
      for (int s = 0; s < 5; ++s) {
        const int gs = sg * 5 + s;
        if (gs < ts) afn[s] = *(const bf16x8*)(apn + gs * 512 + aoff);
      }
    }
    int curbr = -1;
    bf16x8 bq[4];
    #pragma unroll
    for (int s = 0; s < 5; ++s) {
      const int gs = sg * 5 + s;
      if (gs < ts) {
        int br = sbrL[gs];
        if (br != curbr) {
          curbr = br;
          const ushort_t* wp = Wt + ((size_t)br * NKT + kt) * (DIM * BK);
          #pragma unroll
          for (int cf = 0; cf < 4; ++cf) bq[cf] = *(const bf16x8*)(wp + boff[cf]);
        }
        #pragma unroll
        for (int cf = 0; cf < 4; ++cf)
          acc[s][cf] = __builtin_amdgcn_mfma_f32_16x16x32_bf16(afc[s], bq[cf], acc[s][cf], 0, 0, 0);
      }
    }
    if (kt + 1 < NKT) {
      #pragma unroll
      for (int s = 0; s < 5; ++s) afc[s] = afn[s];
    }
  }

  // ---- epilogue: 5 passes of 128 slots through LDS -> natural-order streaming stores ----
  const int row = t & 511;
  const int half = t >> 9;
  float* op = out + ((size_t)w * WIN + row) * DIM + cb * 128 + half * 64;

  #pragma unroll
  for (int p = 0; p < 5; ++p) {
    __syncthreads();
    #pragma unroll
    for (int s = 0; s < 5; ++s) {
      const int gs = sg * 5 + s;
      if (gs >= 8 * p && gs < 8 * p + 8 && gs < ts) {
        const int br = sbrL[gs];
        float bv[4];
        #pragma unroll
        for (int cf = 0; cf < 4; ++cf)
          bv[cf] = bias[br * DIM + colbase + cf * 16 + (l & 15)];
        const int lr0 = (gs - 8 * p) * 16 + (l >> 4) * 4;
        #pragma unroll
        for (int j = 0; j < 4; ++j)
          #pragma unroll
          for (int cf = 0; cf < 4; ++cf)
            OtL[(lr0 + j) * 130 + ch * 64 + cf * 16 + (l & 15)] = acc[s][cf][j] + bv[cf];
      }
    }
    __syncthreads();
    const int lp = (int)myslot - p * 128;
    if (lp >= 0 && lp < 128) {
      const float* lsrc = &OtL[lp * 130 + half * 64];
      #pragma unroll
      for (int q = 0; q < 16; ++q) {
        float2 e0 = *(const float2*)(lsrc + q * 4);
        float2 e1 = *(const float2*)(lsrc + q * 4 + 2);
        float4 vv; vv.x = e0.x; vv.y = e0.y; vv.z = e1.x; vv.w = e1.y;
        *(float4*)(op + q * 4) = vv;
      }
    }
  }
}

// ---------------- launcher ----------------
// ws: [0,4MB) Wt | [4MB,+256KB) smap | +40KB sliceBr | +1KB tsArr | [5MB,..) xT chunk
extern "C" void kernel_launch(void* const* d_in, const int* in_sizes, int n_in,
                              void* d_out, int out_size, void* d_ws, size_t ws_size,
                              hipStream_t stream) {
  const float* x    = (const float*)d_in[0];
  const int*   bidx = (const int*)d_in[1];
  const float* W    = (const float*)d_in[2];
  const float* bias = (const float*)d_in[3];
  float* out = (float*)d_out;

  char* ws = (char*)d_ws;
  ushort_t* Wt = (ushort_t*)ws;
  unsigned short* smap = (unsigned short*)(ws + (4u << 20));
  int* sliceBr = (int*)(ws + (4u << 20) + 262144);
  int* tsArr   = (int*)(ws + (4u << 20) + 262144 + 40960);
  ushort_t* xT = (ushort_t*)(ws + (5u << 20));

  const size_t perWin = (size_t)NKT * SLCAP * BK * 2;   // 655360 B
  size_t avail = ws_size > (5u << 20) ? ws_size - (5u << 20) : 0;
  int WC = 8;
  const int opts[6] = {256, 128, 64, 32, 16, 8};
  for (int i = 0; i < 6; ++i) {
    if ((size_t)opts[i] * perWin <= avail) { WC = opts[i]; break; }
  }

  k_wtrans<<<512, 256, 0, stream>>>(W, Wt);
  k_sort<<<NWIN, WIN, 0, stream>>>(bidx, smap, sliceBr, tsArr);
  for (int w0 = 0; w0 < NWIN; w0 += WC) {
    k_xcvt<<<WC * 4, 512, 0, stream>>>(x, smap, xT, w0);
    k_gemm<<<WC * 4, 1024, 0, stream>>>(xT, Wt, bias, smap, sliceBr, tsArr, out, w0);
  }
}

// Round 8
// 382.406 us; speedup vs baseline: 2.3331x; 2.3331x over previous
//
#include <hip/hip_runtime.h>
#include <hip/hip_bf16.h>
#include <stdint.h>

#define T_TOK 131072
#define DIM   512
#define NBR   8
#define WIN   512                 // tokens per window
#define NWIN  (T_TOK / WIN)       // 256
#define SLCAP 640                 // padded slot capacity (40 slices of 16)
#define NSL   40
#define BK    32
#define NKT   (DIM / BK)          // 16

typedef __attribute__((ext_vector_type(8))) __bf16 bf16x8;
typedef __attribute__((ext_vector_type(4))) float  f32x4;
typedef unsigned short ushort_t;

__device__ __forceinline__ unsigned short f2bf(float f) {
  union { float f; unsigned int u; } v; v.f = f;
  unsigned int r = v.u + 0x7fffu + ((v.u >> 16) & 1u);
  return (unsigned short)(r >> 16);
}

// ---------- W transpose: (N,D,D) f32 -> Wt bf16 [b][kt][col][kk] ----------
__global__ __launch_bounds__(256) void k_wtrans(const float* __restrict__ W,
                                                ushort_t* __restrict__ Wt) {
  __shared__ float tile[BK][129];
  int blk = blockIdx.x;          // 8 * 16 * 4 = 512 blocks
  int b  = blk >> 6;
  int kt = (blk >> 2) & 15;
  int cb = blk & 3;
  int t = threadIdx.x;
  #pragma unroll
  for (int i = 0; i < 4; ++i) {
    int idx4 = i * 256 + t;
    int kr = idx4 >> 5;
    int c4 = idx4 & 31;
    const float* src = W + (((size_t)b * DIM + (size_t)(kt * BK + kr)) * DIM + cb * 128 + c4 * 4);
    float4 v = *(const float4*)src;
    tile[kr][c4 * 4 + 0] = v.x;
    tile[kr][c4 * 4 + 1] = v.y;
    tile[kr][c4 * 4 + 2] = v.z;
    tile[kr][c4 * 4 + 3] = v.w;
  }
  __syncthreads();
  int c  = t >> 1;
  int kh = t & 1;
  unsigned int p[8];
  #pragma unroll
  for (int i = 0; i < 8; ++i) {
    unsigned short lo = f2bf(tile[kh * 16 + i * 2 + 0][c]);
    unsigned short hi = f2bf(tile[kh * 16 + i * 2 + 1][c]);
    p[i] = (unsigned int)lo | ((unsigned int)hi << 16);
  }
  size_t obase = (((size_t)b * 16 + kt) * DIM + (size_t)(cb * 128 + c)) * BK + kh * 16;
  uint4 q0; q0.x = p[0]; q0.y = p[1]; q0.z = p[2]; q0.w = p[3];
  uint4 q1; q1.x = p[4]; q1.y = p[5]; q1.z = p[6]; q1.w = p[7];
  *(uint4*)&Wt[obase]     = q0;
  *(uint4*)&Wt[obase + 8] = q1;
}

// ---------- per-window local sort: smap, slice->branch, slice count ----------
__global__ __launch_bounds__(WIN) void k_sort(const int* __restrict__ bidx,
                                              unsigned short* __restrict__ smap,
                                              int* __restrict__ sliceBr,
                                              int* __restrict__ tsArr) {
  __shared__ int cnt[NBR], ps[NBR], rankL[WIN], bidL[WIN];
  const int w = blockIdx.x;
  const int t = threadIdx.x;
  if (t < NBR) cnt[t] = 0;
  __syncthreads();
  int b = bidx[w * WIN + t];
  bidL[t] = b;
  rankL[t] = atomicAdd(&cnt[b], 1);
  __syncthreads();
  if (t == 0) {
    int s = 0;
    for (int g = 0; g < NBR; ++g) { ps[g] = s; s += (cnt[g] + 15) >> 4; }
    tsArr[w] = s;
  }
  __syncthreads();
  if (t < NSL) {
    int br = -1;
    #pragma unroll
    for (int g = 0; g < NBR; ++g) {
      int sc = (cnt[g] + 15) >> 4;
      if (t >= ps[g] && t < ps[g] + sc) br = g;
    }
    sliceBr[w * NSL + t] = br;
  }
  smap[w * WIN + t] = (unsigned short)(ps[bidL[t]] * 16 + rankL[t]);
}

// ---------- x (f32, natural order, streaming read) -> xT bf16 [w][kt][slot][kk] ----------
__global__ __launch_bounds__(512) void k_xcvt(const float* __restrict__ x,
                                              const unsigned short* __restrict__ smap,
                                              ushort_t* __restrict__ xT, int w0) {
  __shared__ unsigned short slotL[WIN];
  const int bid = blockIdx.x;
  const int w = w0 + (bid >> 2);
  const int part = bid & 3;
  const int t = threadIdx.x;
  slotL[t] = smap[w * WIN + t];
  __syncthreads();
  const float4* xp = (const float4*)(x + (size_t)w * (WIN * DIM));
  ushort_t* xTw = xT + (size_t)(w - w0) * (NKT * SLCAP * BK);
  #pragma unroll 4
  for (int i = 0; i < 32; ++i) {
    int fidx = part * 16384 + i * 512 + t;       // float4 index within window
    float4 v = xp[fidx];
    int row = fidx >> 7;
    int kq4 = fidx & 127;
    int kt = kq4 >> 3;
    int kk = (kq4 & 7) * 4;
    int slot = slotL[row];
    ushort4 a4;
    a4.x = f2bf(v.x); a4.y = f2bf(v.y); a4.z = f2bf(v.z); a4.w = f2bf(v.w);
    *(ushort4*)&xTw[((size_t)kt * SLCAP + slot) * BK + kk] = a4;
  }
}

// ---------- GEMM: col-blocks of a window co-dispatched (bid = w*4+cb) ----------
// 1024 thr = 16 waves = 8 slice-groups x 2 col-halves; wave tile 80x64.
// A inline from L3-resident xT (1KB coalesced); B inline from L2-hot Wt.
__global__ __launch_bounds__(1024, 4)
void k_gemm(const ushort_t* __restrict__ xT, const ushort_t* __restrict__ Wt,
            const float* __restrict__ bias,
            const unsigned short* __restrict__ smap,
            const int* __restrict__ sliceBr, const int* __restrict__ tsArr,
            float* __restrict__ out, int w0) {
  __shared__ float OtL[128 * 130];
  __shared__ int sbrL[NSL];

  const int bid = blockIdx.x;
  const int wloc = bid >> 2;            // co-dispatch the 4 col-blocks of a window
  const int cb = bid & 3;
  const int w = w0 + wloc;
  const int t = threadIdx.x;
  const int l = t & 63;
  const int wv = t >> 6;
  const int ts = tsArr[w];

  if (t < NSL) sbrL[t] = sliceBr[w * NSL + t];
  const unsigned short myslot = smap[w * WIN + (t & 511)];
  __syncthreads();

  const int sg = wv >> 1;               // slice group 0..7
  const int ch = wv & 1;                // col half 0..1
  const int colbase = cb * 128 + ch * 64;

  const ushort_t* xTw = xT + (size_t)wloc * (NKT * SLCAP * BK);
  const int aoff = (l & 15) * BK + (l >> 4) * 8;
  int boff[4];
  #pragma unroll
  for (int cf = 0; cf < 4; ++cf)
    boff[cf] = (colbase + cf * 16 + (l & 15)) * BK + (l >> 4) * 8;

  f32x4 acc[5][4];
  #pragma unroll
  for (int s = 0; s < 5; ++s)
    #pragma unroll
    for (int cf = 0; cf < 4; ++cf) acc[s][cf] = (f32x4){0.f, 0.f, 0.f, 0.f};

  for (int kt = 0; kt < NKT; ++kt) {
    const ushort_t* aplane = xTw + (size_t)kt * (SLCAP * BK);
    int curbr = -1;
    bf16x8 bq[4];
    #pragma unroll
    for (int s = 0; s < 5; ++s) {
      const int gs = sg * 5 + s;
      if (gs < ts) {
        int br = sbrL[gs];
        if (br != curbr) {
          curbr = br;
          const ushort_t* wp = Wt + ((size_t)br * NKT + kt) * (DIM * BK);
          #pragma unroll
          for (int cf = 0; cf < 4; ++cf) bq[cf] = *(const bf16x8*)(wp + boff[cf]);
        }
        bf16x8 af = *(const bf16x8*)(aplane + gs * 512 + aoff);
        #pragma unroll
        for (int cf = 0; cf < 4; ++cf)
          acc[s][cf] = __builtin_amdgcn_mfma_f32_16x16x32_bf16(af, bq[cf], acc[s][cf], 0, 0, 0);
      }
    }
  }

  // ---- epilogue: 5 passes of 128 slots through LDS -> natural-order streaming stores ----
  const int row = t & 511;
  const int half = t >> 9;
  float* op = out + ((size_t)w * WIN + row) * DIM + cb * 128 + half * 64;

  #pragma unroll
  for (int p = 0; p < 5; ++p) {
    __syncthreads();
    #pragma unroll
    for (int s = 0; s < 5; ++s) {
      const int gs = sg * 5 + s;
      if (gs >= 8 * p && gs < 8 * p + 8 && gs < ts) {
        const int br = sbrL[gs];
        float bv[4];
        #pragma unroll
        for (int cf = 0; cf < 4; ++cf)
          bv[cf] = bias[br * DIM + colbase + cf * 16 + (l & 15)];
        const int lr0 = (gs - 8 * p) * 16 + (l >> 4) * 4;
        #pragma unroll
        for (int j = 0; j < 4; ++j)
          #pragma unroll
          for (int cf = 0; cf < 4; ++cf)
            OtL[(lr0 + j) * 130 + ch * 64 + cf * 16 + (l & 15)] = acc[s][cf][j] + bv[cf];
      }
    }
    __syncthreads();
    const int lp = (int)myslot - p * 128;
    if (lp >= 0 && lp < 128) {
      const float* lsrc = &OtL[lp * 130 + half * 64];
      #pragma unroll
      for (int q = 0; q < 16; ++q) {
        float2 e0 = *(const float2*)(lsrc + q * 4);
        float2 e1 = *(const float2*)(lsrc + q * 4 + 2);
        float4 vv; vv.x = e0.x; vv.y = e0.y; vv.z = e1.x; vv.w = e1.y;
        *(float4*)(op + q * 4) = vv;
      }
    }
  }
}

// ---------------- launcher ----------------
// ws: [0,4MB) Wt | [4MB,+256KB) smap | +40KB sliceBr | +1KB tsArr | [5MB,..) xT chunk
extern "C" void kernel_launch(void* const* d_in, const int* in_sizes, int n_in,
                              void* d_out, int out_size, void* d_ws, size_t ws_size,
                              hipStream_t stream) {
  const float* x    = (const float*)d_in[0];
  const int*   bidx = (const int*)d_in[1];
  const float* W    = (const float*)d_in[2];
  const float* bias = (const float*)d_in[3];
  float* out = (float*)d_out;

  char* ws = (char*)d_ws;
  ushort_t* Wt = (ushort_t*)ws;
  unsigned short* smap = (unsigned short*)(ws + (4u << 20));
  int* sliceBr = (int*)(ws + (4u << 20) + 262144);
  int* tsArr   = (int*)(ws + (4u << 20) + 262144 + 40960);
  ushort_t* xT = (ushort_t*)(ws + (5u << 20));

  const size_t perWin = (size_t)NKT * SLCAP * BK * 2;   // 655360 B
  size_t avail = ws_size > (5u << 20) ? ws_size - (5u << 20) : 0;
  // cap chunk at 64 windows (42MB xT) so producer->consumer stays L3-resident
  int WC = 8;
  const int opts[4] = {64, 32, 16, 8};
  for (int i = 0; i < 4; ++i) {
    if ((size_t)opts[i] * perWin <= avail) { WC = opts[i]; break; }
  }

  k_wtrans<<<512, 256, 0, stream>>>(W, Wt);
  k_sort<<<NWIN, WIN, 0, stream>>>(bidx, smap, sliceBr, tsArr);
  for (int w0 = 0; w0 < NWIN; w0 += WC) {
    k_xcvt<<<WC * 4, 512, 0, stream>>>(x, smap, xT, w0);
    k_gemm<<<WC * 4, 1024, 0, stream>>>(xT, Wt, bias, smap, sliceBr, tsArr, out, w0);
  }
}